// Round 2
// baseline (111.568 us; speedup 1.0000x reference)
//
#include <hip/hip_runtime.h>

#define NSEG 64
#define NROW 8192
#define TILE 16
#define WROW 21504
#define NBLK 576          // >= sum ceil(cnt/16) = 512 + 60 worst case

// LDS pitches (floats)
#define PT0 20            // xT0: [128 k][16 r] pitch 20 (16B-aligned rows, 2-way bank alias on store)
#define P1  196           // x1 row-major: [16 r][192]
#define P2  164           // x2 row-major: [16 r][160]

__global__ __launch_bounds__(256) void iil_kernel(
    const float* __restrict__ x0, const float* __restrict__ x1, const float* __restrict__ x2,
    const float* __restrict__ w, const int* __restrict__ counts,
    float* __restrict__ y0, float* __restrict__ y1, float* __restrict__ y2)
{
    __shared__ float xT0[128 * PT0];        // 10240 B
    __shared__ float sx1[TILE * P1];        // 12544 B
    __shared__ float sx2[TILE * P2];        // 10496 B
    __shared__ float w1s[64 * 64];          // 16384 B
    __shared__ int sstart[NSEG + 1];
    __shared__ int tstart[NSEG + 1];

    const int t = threadIdx.x;

    // ---- wave 0: scan counts -> row starts; scan ceil(cnt/16) -> tile starts ----
    if (t < NSEG) {
        int c = counts[t];
        int v = c;
        #pragma unroll
        for (int d = 1; d < NSEG; d <<= 1) {
            int u = __shfl_up(v, d, 64);
            if (t >= d) v += u;
        }
        sstart[t + 1] = v;
        int tcv = (c + TILE - 1) >> 4;
        #pragma unroll
        for (int d = 1; d < NSEG; d <<= 1) {
            int u = __shfl_up(tcv, d, 64);
            if (t >= d) tcv += u;
        }
        tstart[t + 1] = tcv;
        if (t == 0) { sstart[0] = 0; tstart[0] = 0; }
    }
    __syncthreads();

    const int b = blockIdx.x;
    if (b >= tstart[NSEG]) return;          // uniform per block

    // find segment g: tstart[g] <= b < tstart[g+1]
    int lo = 0, hi = NSEG;
    while (hi - lo > 1) {
        int mid = (lo + hi) >> 1;
        if (tstart[mid] <= b) lo = mid; else hi = mid;
    }
    const int g = lo;
    const int s = sstart[g] + (b - tstart[g]) * TILE;   // first row of this tile
    const int nr = min(TILE, sstart[g + 1] - s);        // rows in this tile
    const float* __restrict__ wseg = w + (size_t)g * WROW;

    // ---- stage x (zero-pad dead rows), stage W1 ----
    {
        const float4 z4 = make_float4(0.f, 0.f, 0.f, 0.f);
        // x0 -> transposed xT0[k][r]
        const float4* g0 = (const float4*)x0 + (size_t)s * 32;
        #pragma unroll
        for (int i = 0; i < 2; ++i) {                    // 512 float4
            int idx = t + i * 256;
            int r = idx >> 5, c4 = idx & 31;
            float4 v = (r < nr) ? g0[idx] : z4;
            xT0[(c4 * 4 + 0) * PT0 + r] = v.x;
            xT0[(c4 * 4 + 1) * PT0 + r] = v.y;
            xT0[(c4 * 4 + 2) * PT0 + r] = v.z;
            xT0[(c4 * 4 + 3) * PT0 + r] = v.w;
        }
        // x1 row-major
        const float4* g1 = (const float4*)x1 + (size_t)s * 48;
        #pragma unroll
        for (int i = 0; i < 3; ++i) {                    // 768 float4
            int idx = t + i * 256;
            int r = idx / 48, c = idx - r * 48;
            float4 v = (r < nr) ? g1[idx] : z4;
            *(float4*)(sx1 + r * P1 + c * 4) = v;
        }
        // x2 row-major
        const float4* g2 = (const float4*)x2 + (size_t)s * 40;
        #pragma unroll
        for (int i = 0; i < 3; ++i) {                    // 640 float4
            int idx = t + i * 256;
            if (idx < 640) {
                int r = idx / 40, c = idx - r * 40;
                float4 v = (r < nr) ? g2[idx] : z4;
                *(float4*)(sx2 + r * P2 + c * 4) = v;
            }
        }
        // W1 block (64x64) -> LDS
        const float4* gw1 = (const float4*)(wseg + 16384);
        #pragma unroll
        for (int i = 0; i < 4; ++i) {                    // 1024 float4
            int idx = t + i * 256;
            *(float4*)(w1s + idx * 4) = gw1[idx];
        }
    }
    __syncthreads();

    // ---- phase 0: mul=128, dim=1.  thread = (og in 64 -> 2 outs, rg in 4 -> 4 rows) ----
    {
        const int og = t & 63;
        const int rg = t >> 6;
        const float* wp = wseg + og * 2;
        const float* xb = xT0 + rg * 4;
        float acc[8];
        #pragma unroll
        for (int i = 0; i < 8; ++i) acc[i] = 0.f;
        #pragma unroll 4
        for (int k = 0; k < 128; ++k) {
            float4 xv = *(const float4*)(xb + k * PT0);   // broadcast within wave
            float2 wv = *(const float2*)(wp + (size_t)k * 128);
            acc[0] = fmaf(xv.x, wv.x, acc[0]);
            acc[1] = fmaf(xv.x, wv.y, acc[1]);
            acc[2] = fmaf(xv.y, wv.x, acc[2]);
            acc[3] = fmaf(xv.y, wv.y, acc[3]);
            acc[4] = fmaf(xv.z, wv.x, acc[4]);
            acc[5] = fmaf(xv.z, wv.y, acc[5]);
            acc[6] = fmaf(xv.w, wv.x, acc[6]);
            acc[7] = fmaf(xv.w, wv.y, acc[7]);
        }
        const float c0 = 0.011048543456039806f;  // 1/(8*sqrt(128))
        #pragma unroll
        for (int jr = 0; jr < 4; ++jr) {
            int r = rg * 4 + jr;
            if (r < nr) {
                float2 v = make_float2(acc[jr * 2] * c0, acc[jr * 2 + 1] * c0);
                *(float2*)(y0 + (size_t)(s + r) * 128 + og * 2) = v;
            }
        }
    }

    // ---- phase 1: mul=64, dim=3.  thread = (og in 16 -> 4 outs, r in 16) ----
    {
        const int og = t & 15;
        const int r = t >> 4;
        const float* xrow = sx1 + r * P1;
        float acc[12];
        #pragma unroll
        for (int i = 0; i < 12; ++i) acc[i] = 0.f;
        #pragma unroll 2
        for (int kq = 0; kq < 16; ++kq) {
            float4 xq0 = *(const float4*)(xrow + 12 * kq + 0);
            float4 xq1 = *(const float4*)(xrow + 12 * kq + 4);
            float4 xq2 = *(const float4*)(xrow + 12 * kq + 8);
            float xf[12] = {xq0.x, xq0.y, xq0.z, xq0.w,
                            xq1.x, xq1.y, xq1.z, xq1.w,
                            xq2.x, xq2.y, xq2.z, xq2.w};
            #pragma unroll
            for (int kk = 0; kk < 4; ++kk) {
                int k = 4 * kq + kk;
                float4 wv = *(const float4*)(w1s + k * 64 + og * 4);
                #pragma unroll
                for (int oo = 0; oo < 4; ++oo) {
                    float wvo = (oo == 0) ? wv.x : (oo == 1) ? wv.y : (oo == 2) ? wv.z : wv.w;
                    acc[oo * 3 + 0] = fmaf(wvo, xf[kk * 3 + 0], acc[oo * 3 + 0]);
                    acc[oo * 3 + 1] = fmaf(wvo, xf[kk * 3 + 1], acc[oo * 3 + 1]);
                    acc[oo * 3 + 2] = fmaf(wvo, xf[kk * 3 + 2], acc[oo * 3 + 2]);
                }
            }
        }
        const float c1 = 0.015625f;      // 1/(8*8)
        if (r < nr) {
            float* yb = y1 + (size_t)(s + r) * 192 + og * 12;
            *(float4*)(yb + 0) = make_float4(acc[0] * c1, acc[1] * c1, acc[2] * c1, acc[3] * c1);
            *(float4*)(yb + 4) = make_float4(acc[4] * c1, acc[5] * c1, acc[6] * c1, acc[7] * c1);
            *(float4*)(yb + 8) = make_float4(acc[8] * c1, acc[9] * c1, acc[10] * c1, acc[11] * c1);
        }
    }

    // ---- phase 2: mul=32, dim=5.  thread = (og in 16 -> 2 outs, r in 16) ----
    {
        const int og = t & 15;
        const int r = t >> 4;
        const float* xrow = sx2 + r * P2;
        const float* wp = wseg + 20480 + og * 2;
        float acc[10];
        #pragma unroll
        for (int i = 0; i < 10; ++i) acc[i] = 0.f;
        #pragma unroll
        for (int kq = 0; kq < 8; ++kq) {
            float xf[20];
            #pragma unroll
            for (int j = 0; j < 5; ++j) {
                float4 v = *(const float4*)(xrow + 20 * kq + 4 * j);
                xf[4 * j + 0] = v.x; xf[4 * j + 1] = v.y; xf[4 * j + 2] = v.z; xf[4 * j + 3] = v.w;
            }
            #pragma unroll
            for (int kk = 0; kk < 4; ++kk) {
                int k = 4 * kq + kk;
                float2 wv = *(const float2*)(wp + (size_t)k * 32);
                #pragma unroll
                for (int i = 0; i < 5; ++i) {
                    acc[i]     = fmaf(wv.x, xf[5 * kk + i], acc[i]);
                    acc[5 + i] = fmaf(wv.y, xf[5 * kk + i], acc[5 + i]);
                }
            }
        }
        const float c2 = 0.022097086912079608f;  // 1/(8*sqrt(32))
        if (r < nr) {
            float* yb = y2 + (size_t)(s + r) * 160 + og * 10;
            #pragma unroll
            for (int i = 0; i < 5; ++i) {
                *(float2*)(yb + 2 * i) = make_float2(acc[2 * i] * c2, acc[2 * i + 1] * c2);
            }
        }
    }
}

extern "C" void kernel_launch(void* const* d_in, const int* in_sizes, int n_in,
                              void* d_out, int out_size, void* d_ws, size_t ws_size,
                              hipStream_t stream) {
    const float* x0 = (const float*)d_in[0];
    const float* x1 = (const float*)d_in[1];
    const float* x2 = (const float*)d_in[2];
    const float* w  = (const float*)d_in[3];
    const int* counts = (const int*)d_in[4];

    float* y0 = (float*)d_out;
    float* y1 = y0 + (size_t)NROW * 128;
    float* y2 = y1 + (size_t)NROW * 192;

    hipLaunchKernelGGL(iil_kernel, dim3(NBLK), dim3(256), 0, stream,
                       x0, x1, x2, w, counts, y0, y1, y2);
}

// Round 3
// 96.591 us; speedup vs baseline: 1.1551x; 1.1551x over previous
//
#include <hip/hip_runtime.h>

#define NSEG 64
#define NROW 8192
#define TILE 16
#define WROW 21504
#define NBPP 576          // blocks per phase: >= sum ceil(cnt/16) <= 512+64
#define PT0 20            // xT0: [128 k][16 r] pitch 20
#define P1  196           // x1 row-major: [16 r][192+4]
#define P2  164           // x2 row-major: [16 r][160+4]

__global__ __launch_bounds__(256) void iil_kernel(
    const float* __restrict__ x0, const float* __restrict__ x1, const float* __restrict__ x2,
    const float* __restrict__ w, const int* __restrict__ counts,
    float* __restrict__ y0, float* __restrict__ y1, float* __restrict__ y2)
{
    __shared__ float sbuf[TILE * P1];   // union: phase0 2560, phase1 3136, phase2 2624 floats
    __shared__ int sstart[NSEG + 1];
    __shared__ int tstart[NSEG + 1];

    const int t = threadIdx.x;

    // ---- wave 0: scan counts -> row starts; scan ceil(cnt/16) -> tile starts ----
    if (t < NSEG) {
        int c = counts[t];
        int v = c;
        #pragma unroll
        for (int d = 1; d < NSEG; d <<= 1) {
            int u = __shfl_up(v, d, 64);
            if (t >= d) v += u;
        }
        sstart[t + 1] = v;
        int tc = (c + TILE - 1) >> 4;
        #pragma unroll
        for (int d = 1; d < NSEG; d <<= 1) {
            int u = __shfl_up(tc, d, 64);
            if (t >= d) tc += u;
        }
        tstart[t + 1] = tc;
        if (t == 0) { sstart[0] = 0; tstart[0] = 0; }
    }
    __syncthreads();

    const int phase = blockIdx.x / NBPP;
    const int pb = blockIdx.x - phase * NBPP;
    if (pb >= tstart[NSEG]) return;     // uniform per block

    // segment g: tstart[g] <= pb < tstart[g+1]
    int lo = 0, hi = NSEG;
    while (hi - lo > 1) {
        int mid = (lo + hi) >> 1;
        if (tstart[mid] <= pb) lo = mid; else hi = mid;
    }
    const int g = lo;
    const int s = sstart[g] + (pb - tstart[g]) * TILE;
    const int nr = min(TILE, sstart[g + 1] - s);
    const float* __restrict__ wseg = w + (size_t)g * WROW;
    const float4 z4 = make_float4(0.f, 0.f, 0.f, 0.f);

    if (phase == 0) {
        // ---- stage x0 transposed: xT0[k][r], pitch 20 ----
        float* xT0 = sbuf;
        const float4* g0 = (const float4*)x0 + (size_t)s * 32;
        #pragma unroll
        for (int i = 0; i < 2; ++i) {                 // 512 float4
            int idx = t + i * 256;
            int r = idx >> 5, c4 = idx & 31;
            float4 v = (r < nr) ? g0[idx] : z4;
            xT0[(c4 * 4 + 0) * PT0 + r] = v.x;
            xT0[(c4 * 4 + 1) * PT0 + r] = v.y;
            xT0[(c4 * 4 + 2) * PT0 + r] = v.z;
            xT0[(c4 * 4 + 3) * PT0 + r] = v.w;
        }
        __syncthreads();
        // ---- thread = (og in 32 -> 4 outs, rg in 8 -> 2 rows) ----
        const int og = t & 31;
        const int rg = t >> 5;
        const float* wp = wseg + og * 4;
        const float* xb = xT0 + rg * 2;
        float acc[8];
        #pragma unroll
        for (int i = 0; i < 8; ++i) acc[i] = 0.f;
        #pragma unroll 8
        for (int k = 0; k < 128; ++k) {
            float2 xv = *(const float2*)(xb + k * PT0);          // broadcast
            float4 wv = *(const float4*)(wp + (size_t)k * 128);  // coalesced 512B/wave
            acc[0] = fmaf(xv.x, wv.x, acc[0]);
            acc[1] = fmaf(xv.x, wv.y, acc[1]);
            acc[2] = fmaf(xv.x, wv.z, acc[2]);
            acc[3] = fmaf(xv.x, wv.w, acc[3]);
            acc[4] = fmaf(xv.y, wv.x, acc[4]);
            acc[5] = fmaf(xv.y, wv.y, acc[5]);
            acc[6] = fmaf(xv.y, wv.z, acc[6]);
            acc[7] = fmaf(xv.y, wv.w, acc[7]);
        }
        const float c0 = 0.011048543456039806f;  // 1/(8*sqrt(128))
        int r0 = rg * 2;
        if (r0 < nr)
            *(float4*)(y0 + (size_t)(s + r0) * 128 + og * 4) =
                make_float4(acc[0] * c0, acc[1] * c0, acc[2] * c0, acc[3] * c0);
        if (r0 + 1 < nr)
            *(float4*)(y0 + (size_t)(s + r0 + 1) * 128 + og * 4) =
                make_float4(acc[4] * c0, acc[5] * c0, acc[6] * c0, acc[7] * c0);
    } else if (phase == 1) {
        // ---- stage x1 row-major ----
        float* sx1 = sbuf;
        const float4* g1 = (const float4*)x1 + (size_t)s * 48;
        #pragma unroll
        for (int i = 0; i < 3; ++i) {                 // 768 float4
            int idx = t + i * 256;
            int r = idx / 48, c = idx - r * 48;
            float4 v = (r < nr) ? g1[idx] : z4;
            *(float4*)(sx1 + r * P1 + c * 4) = v;
        }
        __syncthreads();
        // ---- thread = (og in 16 -> 4 outs, r in 16) ----
        const int og = t & 15;
        const int r = t >> 4;
        const float* xrow = sx1 + r * P1;
        const float* wp = wseg + 16384 + og * 4;
        float acc[12];
        #pragma unroll
        for (int i = 0; i < 12; ++i) acc[i] = 0.f;
        #pragma unroll 2
        for (int kq = 0; kq < 16; ++kq) {
            float4 xq0 = *(const float4*)(xrow + 12 * kq + 0);
            float4 xq1 = *(const float4*)(xrow + 12 * kq + 4);
            float4 xq2 = *(const float4*)(xrow + 12 * kq + 8);
            float xf[12] = {xq0.x, xq0.y, xq0.z, xq0.w,
                            xq1.x, xq1.y, xq1.z, xq1.w,
                            xq2.x, xq2.y, xq2.z, xq2.w};
            #pragma unroll
            for (int kk = 0; kk < 4; ++kk) {
                float4 wv = *(const float4*)(wp + (size_t)(4 * kq + kk) * 64);
                #pragma unroll
                for (int oo = 0; oo < 4; ++oo) {
                    float wvo = (oo == 0) ? wv.x : (oo == 1) ? wv.y : (oo == 2) ? wv.z : wv.w;
                    acc[oo * 3 + 0] = fmaf(wvo, xf[kk * 3 + 0], acc[oo * 3 + 0]);
                    acc[oo * 3 + 1] = fmaf(wvo, xf[kk * 3 + 1], acc[oo * 3 + 1]);
                    acc[oo * 3 + 2] = fmaf(wvo, xf[kk * 3 + 2], acc[oo * 3 + 2]);
                }
            }
        }
        const float c1 = 0.015625f;      // 1/(8*8)
        if (r < nr) {
            float* yb = y1 + (size_t)(s + r) * 192 + og * 12;
            *(float4*)(yb + 0) = make_float4(acc[0] * c1, acc[1] * c1, acc[2] * c1, acc[3] * c1);
            *(float4*)(yb + 4) = make_float4(acc[4] * c1, acc[5] * c1, acc[6] * c1, acc[7] * c1);
            *(float4*)(yb + 8) = make_float4(acc[8] * c1, acc[9] * c1, acc[10] * c1, acc[11] * c1);
        }
    } else {
        // ---- stage x2 row-major ----
        float* sx2 = sbuf;
        const float4* g2 = (const float4*)x2 + (size_t)s * 40;
        #pragma unroll
        for (int i = 0; i < 3; ++i) {                 // 640 float4
            int idx = t + i * 256;
            if (idx < 640) {
                int r = idx / 40, c = idx - r * 40;
                float4 v = (r < nr) ? g2[idx] : z4;
                *(float4*)(sx2 + r * P2 + c * 4) = v;
            }
        }
        __syncthreads();
        // ---- thread = (og in 16 -> 2 outs, r in 16) ----
        const int og = t & 15;
        const int r = t >> 4;
        const float* xrow = sx2 + r * P2;
        const float* wp = wseg + 20480 + og * 2;
        float acc[10];
        #pragma unroll
        for (int i = 0; i < 10; ++i) acc[i] = 0.f;
        #pragma unroll
        for (int kq = 0; kq < 8; ++kq) {
            float xf[20];
            #pragma unroll
            for (int j = 0; j < 5; ++j) {
                float4 v = *(const float4*)(xrow + 20 * kq + 4 * j);
                xf[4 * j + 0] = v.x; xf[4 * j + 1] = v.y; xf[4 * j + 2] = v.z; xf[4 * j + 3] = v.w;
            }
            #pragma unroll
            for (int kk = 0; kk < 4; ++kk) {
                float2 wv = *(const float2*)(wp + (size_t)(4 * kq + kk) * 32);
                #pragma unroll
                for (int i = 0; i < 5; ++i) {
                    acc[i]     = fmaf(wv.x, xf[5 * kk + i], acc[i]);
                    acc[5 + i] = fmaf(wv.y, xf[5 * kk + i], acc[5 + i]);
                }
            }
        }
        const float c2 = 0.022097086912079608f;  // 1/(8*sqrt(32))
        if (r < nr) {
            float* yb = y2 + (size_t)(s + r) * 160 + og * 10;
            #pragma unroll
            for (int i = 0; i < 5; ++i)
                *(float2*)(yb + 2 * i) = make_float2(acc[2 * i] * c2, acc[2 * i + 1] * c2);
        }
    }
}

extern "C" void kernel_launch(void* const* d_in, const int* in_sizes, int n_in,
                              void* d_out, int out_size, void* d_ws, size_t ws_size,
                              hipStream_t stream) {
    const float* x0 = (const float*)d_in[0];
    const float* x1 = (const float*)d_in[1];
    const float* x2 = (const float*)d_in[2];
    const float* w  = (const float*)d_in[3];
    const int* counts = (const int*)d_in[4];

    float* y0 = (float*)d_out;
    float* y1 = y0 + (size_t)NROW * 128;
    float* y2 = y1 + (size_t)NROW * 192;

    hipLaunchKernelGGL(iil_kernel, dim3(3 * NBPP), dim3(256), 0, stream,
                       x0, x1, x2, w, counts, y0, y1, y2);
}

// Round 4
// 90.847 us; speedup vs baseline: 1.2281x; 1.0632x over previous
//
#include <hip/hip_runtime.h>

#define NSEG 64
#define NROW 8192
#define WROW 21504
#define NBPP 576          // blocks per phase slot
#define T0   32           // phase-0 row tile
#define T12  16           // phase-1/2 row tile
#define PX0  132          // x0 LDS pitch: 132%32=4 -> 8 rows span disjoint bank quads
#define P1   196
#define P2   164
#define SBUF_FLOATS 4224  // max(32*132, 16*196, 16*164)

__global__ __launch_bounds__(256) void iil_kernel(
    const float* __restrict__ x0, const float* __restrict__ x1, const float* __restrict__ x2,
    const float* __restrict__ w, const int* __restrict__ counts,
    float* __restrict__ y0, float* __restrict__ y1, float* __restrict__ y2)
{
    __shared__ float sbuf[SBUF_FLOATS];
    __shared__ int sstart[NSEG + 1];
    __shared__ int t16s[NSEG + 1];
    __shared__ int t32s[NSEG + 1];

    const int t = threadIdx.x;

    // ---- wave 0: scans: rows, ceil(cnt/16) tiles, ceil(cnt/32) tiles ----
    if (t < NSEG) {
        int c = counts[t];
        int v = c;
        #pragma unroll
        for (int d = 1; d < NSEG; d <<= 1) {
            int u = __shfl_up(v, d, 64);
            if (t >= d) v += u;
        }
        sstart[t + 1] = v;
        int a = (c + 15) >> 4;
        #pragma unroll
        for (int d = 1; d < NSEG; d <<= 1) {
            int u = __shfl_up(a, d, 64);
            if (t >= d) a += u;
        }
        t16s[t + 1] = a;
        int b2 = (c + 31) >> 5;
        #pragma unroll
        for (int d = 1; d < NSEG; d <<= 1) {
            int u = __shfl_up(b2, d, 64);
            if (t >= d) b2 += u;
        }
        t32s[t + 1] = b2;
        if (t == 0) { sstart[0] = 0; t16s[0] = 0; t32s[0] = 0; }
    }
    __syncthreads();

    const int phase = blockIdx.x / NBPP;
    const int pb = blockIdx.x - phase * NBPP;
    const float4 z4 = make_float4(0.f, 0.f, 0.f, 0.f);

    if (phase == 0) {
        if (pb >= t32s[NSEG]) return;
        int lo = 0, hi = NSEG;
        while (hi - lo > 1) {
            int mid = (lo + hi) >> 1;
            if (t32s[mid] <= pb) lo = mid; else hi = mid;
        }
        const int g = lo;
        const int s = sstart[g] + (pb - t32s[g]) * T0;
        const int nr = min(T0, sstart[g + 1] - s);
        const float* __restrict__ wseg = w + (size_t)g * WROW;

        // ---- stage x0 row-major, pitch 132, zero-pad dead rows ----
        const float4* g0 = (const float4*)x0 + (size_t)s * 32;
        #pragma unroll
        for (int i = 0; i < 4; ++i) {               // 1024 float4
            int idx = t + i * 256;
            int r = idx >> 5, c4 = idx & 31;
            float4 v = (r < nr) ? g0[idx] : z4;
            *(float4*)(sbuf + r * PX0 + c4 * 4) = v;
        }
        __syncthreads();

        // ---- thread = (og in 32 -> 4 outs, rg in 8 -> 4 rows) ----
        const int og = t & 31;
        const int rg = t >> 5;
        const float* wp = wseg + og * 4;
        const float* xb = sbuf + rg * 4 * PX0;
        float acc[16];
        #pragma unroll
        for (int i = 0; i < 16; ++i) acc[i] = 0.f;

        #pragma unroll 2
        for (int kq = 0; kq < 32; ++kq) {
            const int k = kq * 4;
            float4 xq0 = *(const float4*)(xb + 0 * PX0 + k);
            float4 xq1 = *(const float4*)(xb + 1 * PX0 + k);
            float4 xq2 = *(const float4*)(xb + 2 * PX0 + k);
            float4 xq3 = *(const float4*)(xb + 3 * PX0 + k);
            float4 w0q = *(const float4*)(wp + (size_t)(k + 0) * 128);
            float4 w1q = *(const float4*)(wp + (size_t)(k + 1) * 128);
            float4 w2q = *(const float4*)(wp + (size_t)(k + 2) * 128);
            float4 w3q = *(const float4*)(wp + (size_t)(k + 3) * 128);
#define RF(J, XQ)                                              \
            acc[J*4+0] = fmaf(XQ.x, w0q.x, acc[J*4+0]);        \
            acc[J*4+1] = fmaf(XQ.x, w0q.y, acc[J*4+1]);        \
            acc[J*4+2] = fmaf(XQ.x, w0q.z, acc[J*4+2]);        \
            acc[J*4+3] = fmaf(XQ.x, w0q.w, acc[J*4+3]);        \
            acc[J*4+0] = fmaf(XQ.y, w1q.x, acc[J*4+0]);        \
            acc[J*4+1] = fmaf(XQ.y, w1q.y, acc[J*4+1]);        \
            acc[J*4+2] = fmaf(XQ.y, w1q.z, acc[J*4+2]);        \
            acc[J*4+3] = fmaf(XQ.y, w1q.w, acc[J*4+3]);        \
            acc[J*4+0] = fmaf(XQ.z, w2q.x, acc[J*4+0]);        \
            acc[J*4+1] = fmaf(XQ.z, w2q.y, acc[J*4+1]);        \
            acc[J*4+2] = fmaf(XQ.z, w2q.z, acc[J*4+2]);        \
            acc[J*4+3] = fmaf(XQ.z, w2q.w, acc[J*4+3]);        \
            acc[J*4+0] = fmaf(XQ.w, w3q.x, acc[J*4+0]);        \
            acc[J*4+1] = fmaf(XQ.w, w3q.y, acc[J*4+1]);        \
            acc[J*4+2] = fmaf(XQ.w, w3q.z, acc[J*4+2]);        \
            acc[J*4+3] = fmaf(XQ.w, w3q.w, acc[J*4+3]);
            RF(0, xq0)
            RF(1, xq1)
            RF(2, xq2)
            RF(3, xq3)
#undef RF
        }
        const float c0 = 0.011048543456039806f;  // 1/(8*sqrt(128))
        #pragma unroll
        for (int j = 0; j < 4; ++j) {
            int r = rg * 4 + j;
            if (r < nr) {
                *(float4*)(y0 + (size_t)(s + r) * 128 + og * 4) =
                    make_float4(acc[j*4+0] * c0, acc[j*4+1] * c0,
                                acc[j*4+2] * c0, acc[j*4+3] * c0);
            }
        }
    } else if (phase == 1) {
        if (pb >= t16s[NSEG]) return;
        int lo = 0, hi = NSEG;
        while (hi - lo > 1) {
            int mid = (lo + hi) >> 1;
            if (t16s[mid] <= pb) lo = mid; else hi = mid;
        }
        const int g = lo;
        const int s = sstart[g] + (pb - t16s[g]) * T12;
        const int nr = min(T12, sstart[g + 1] - s);
        const float* __restrict__ wseg = w + (size_t)g * WROW;

        float* sx1 = sbuf;
        const float4* g1 = (const float4*)x1 + (size_t)s * 48;
        #pragma unroll
        for (int i = 0; i < 3; ++i) {               // 768 float4
            int idx = t + i * 256;
            int r = idx / 48, c = idx - r * 48;
            float4 v = (r < nr) ? g1[idx] : z4;
            *(float4*)(sx1 + r * P1 + c * 4) = v;
        }
        __syncthreads();

        const int og = t & 15;
        const int r = t >> 4;
        const float* xrow = sx1 + r * P1;
        const float* wp = wseg + 16384 + og * 4;
        float acc[12];
        #pragma unroll
        for (int i = 0; i < 12; ++i) acc[i] = 0.f;
        #pragma unroll 2
        for (int kq = 0; kq < 16; ++kq) {
            float4 xq0 = *(const float4*)(xrow + 12 * kq + 0);
            float4 xq1 = *(const float4*)(xrow + 12 * kq + 4);
            float4 xq2 = *(const float4*)(xrow + 12 * kq + 8);
            float xf[12] = {xq0.x, xq0.y, xq0.z, xq0.w,
                            xq1.x, xq1.y, xq1.z, xq1.w,
                            xq2.x, xq2.y, xq2.z, xq2.w};
            #pragma unroll
            for (int kk = 0; kk < 4; ++kk) {
                float4 wv = *(const float4*)(wp + (size_t)(4 * kq + kk) * 64);
                #pragma unroll
                for (int oo = 0; oo < 4; ++oo) {
                    float wvo = (oo == 0) ? wv.x : (oo == 1) ? wv.y : (oo == 2) ? wv.z : wv.w;
                    acc[oo * 3 + 0] = fmaf(wvo, xf[kk * 3 + 0], acc[oo * 3 + 0]);
                    acc[oo * 3 + 1] = fmaf(wvo, xf[kk * 3 + 1], acc[oo * 3 + 1]);
                    acc[oo * 3 + 2] = fmaf(wvo, xf[kk * 3 + 2], acc[oo * 3 + 2]);
                }
            }
        }
        const float c1 = 0.015625f;      // 1/(8*8)
        if (r < nr) {
            float* yb = y1 + (size_t)(s + r) * 192 + og * 12;
            *(float4*)(yb + 0) = make_float4(acc[0] * c1, acc[1] * c1, acc[2] * c1, acc[3] * c1);
            *(float4*)(yb + 4) = make_float4(acc[4] * c1, acc[5] * c1, acc[6] * c1, acc[7] * c1);
            *(float4*)(yb + 8) = make_float4(acc[8] * c1, acc[9] * c1, acc[10] * c1, acc[11] * c1);
        }
    } else {
        if (pb >= t16s[NSEG]) return;
        int lo = 0, hi = NSEG;
        while (hi - lo > 1) {
            int mid = (lo + hi) >> 1;
            if (t16s[mid] <= pb) lo = mid; else hi = mid;
        }
        const int g = lo;
        const int s = sstart[g] + (pb - t16s[g]) * T12;
        const int nr = min(T12, sstart[g + 1] - s);
        const float* __restrict__ wseg = w + (size_t)g * WROW;

        float* sx2 = sbuf;
        const float4* g2 = (const float4*)x2 + (size_t)s * 40;
        #pragma unroll
        for (int i = 0; i < 3; ++i) {               // 640 float4
            int idx = t + i * 256;
            if (idx < 640) {
                int r = idx / 40, c = idx - r * 40;
                float4 v = (r < nr) ? g2[idx] : z4;
                *(float4*)(sx2 + r * P2 + c * 4) = v;
            }
        }
        __syncthreads();

        const int og = t & 15;
        const int r = t >> 4;
        const float* xrow = sx2 + r * P2;
        const float* wp = wseg + 20480 + og * 2;
        float acc[10];
        #pragma unroll
        for (int i = 0; i < 10; ++i) acc[i] = 0.f;
        #pragma unroll
        for (int kq = 0; kq < 8; ++kq) {
            float xf[20];
            #pragma unroll
            for (int j = 0; j < 5; ++j) {
                float4 v = *(const float4*)(xrow + 20 * kq + 4 * j);
                xf[4 * j + 0] = v.x; xf[4 * j + 1] = v.y; xf[4 * j + 2] = v.z; xf[4 * j + 3] = v.w;
            }
            #pragma unroll
            for (int kk = 0; kk < 4; ++kk) {
                float2 wv = *(const float2*)(wp + (size_t)(4 * kq + kk) * 32);
                #pragma unroll
                for (int i = 0; i < 5; ++i) {
                    acc[i]     = fmaf(wv.x, xf[5 * kk + i], acc[i]);
                    acc[5 + i] = fmaf(wv.y, xf[5 * kk + i], acc[5 + i]);
                }
            }
        }
        const float c2 = 0.022097086912079608f;  // 1/(8*sqrt(32))
        if (r < nr) {
            float* yb = y2 + (size_t)(s + r) * 160 + og * 10;
            #pragma unroll
            for (int i = 0; i < 5; ++i)
                *(float2*)(yb + 2 * i) = make_float2(acc[2 * i] * c2, acc[2 * i + 1] * c2);
        }
    }
}

extern "C" void kernel_launch(void* const* d_in, const int* in_sizes, int n_in,
                              void* d_out, int out_size, void* d_ws, size_t ws_size,
                              hipStream_t stream) {
    const float* x0 = (const float*)d_in[0];
    const float* x1 = (const float*)d_in[1];
    const float* x2 = (const float*)d_in[2];
    const float* w  = (const float*)d_in[3];
    const int* counts = (const int*)d_in[4];

    float* y0 = (float*)d_out;
    float* y1 = y0 + (size_t)NROW * 128;
    float* y2 = y1 + (size_t)NROW * 192;

    hipLaunchKernelGGL(iil_kernel, dim3(3 * NBPP), dim3(256), 0, stream,
                       x0, x1, x2, w, counts, y0, y1, y2);
}